// Round 7
// baseline (334.354 us; speedup 1.0000x reference)
//
#include <hip/hip_runtime.h>

// SelfAttention: B=4, L=4096, H=256, fp32 in/out.
// Round 7: issue-load reduction on the r6 skeleton.
//  - K staging via __builtin_amdgcn_global_load_lds width=16 (async DMA, no
//    reg round-trip, -32 VGPR, drains at the existing per-iter barrier).
//  - Alpha-skip: wave-uniform branch skips O-rescale when no row max updated
//    (near-one-hot logits -> ~94% of iters skip).
//  - qkv: frag-linear W read coalesced direct from L2 (no W LDS staging,
//    2 barriers only for the 18.4 KB epilogue transpose), launch_bounds(256,3)
//    (live-regs ~110 < 170 cap — r5's spill was attn's 230-reg live set).
// Precision: split-bf16 3-product QK (fp32-accurate logits), bf16 PV, bf16
// O-partials. Measured absmax 0.25 @ threshold 1.01.

typedef __bf16 bf16x8 __attribute__((ext_vector_type(8)));
typedef __bf16 bf16x4 __attribute__((ext_vector_type(4)));
typedef float floatx4 __attribute__((ext_vector_type(4)));

#define MFMA16(a, b, c) __builtin_amdgcn_mfma_f32_16x16x32_bf16(a, b, c, 0, 0, 0)
#define GLOAD_LDS16(g, l)                                                  \
  __builtin_amdgcn_global_load_lds(                                        \
      (const __attribute__((address_space(1))) void *)(g),                 \
      (__attribute__((address_space(3))) void *)(l), 16, 0, 0)

#define HID 256
#define LSEQ 4096
#define NB 4
#define NTOK (NB * LSEQ)             // 16384
#define PLANE ((size_t)NTOK * HID)   // 4,194,304 elements
#define QSCALE 0.09016844005556021f  // log2(e)/16 ; softmax uses exp2

// Layouts:
//  Whf/Wlf [w(3)][ct(16)][kc(8)][lane(64)][j(8)] : B-frag-linear weights.
//  Kf (32-key tiles, T = tok>>5, 512 tiles): [T][hi/lo][nt(2)][kc(8)][lane][j],
//    tile stride 16384 el (hi 0..8191, lo +8192).
//  Vf (32-key tiles): [T][dt(16)][lane][j], tile stride 8192 el.

__device__ __forceinline__ void split_bf16(float v, __bf16 &h, __bf16 &l) {
  h = (__bf16)v;
  l = (__bf16)(v - (float)h);
}

// DPP 16-lane-row butterfly reductions (VALU, no LDS pipe).
template <int N>
__device__ __forceinline__ float dpp_ror(float v) {
  return __builtin_bit_cast(float,
      __builtin_amdgcn_update_dpp(0, __builtin_bit_cast(int, v),
                                  0x120 + N, 0xf, 0xf, true));
}
__device__ __forceinline__ float row_sum16(float v) {
  v += dpp_ror<1>(v);
  v += dpp_ror<2>(v);
  v += dpp_ror<4>(v);
  v += dpp_ror<8>(v);
  return v;
}
__device__ __forceinline__ float row_max16(float v) {
  v = fmaxf(v, dpp_ror<1>(v));
  v = fmaxf(v, dpp_ror<2>(v));
  v = fmaxf(v, dpp_ror<4>(v));
  v = fmaxf(v, dpp_ror<8>(v));
  return v;
}

// ---------------------------------------------------------------------------
// Kernel 1: hi/lo-split weights -> fragment-linear Whf/Wlf.
// ---------------------------------------------------------------------------
__global__ __launch_bounds__(256) void wsplit(const float *__restrict__ Wq,
                                              const float *__restrict__ Wk,
                                              const float *__restrict__ Wv,
                                              __bf16 *__restrict__ Whf,
                                              __bf16 *__restrict__ Wlf) {
  __shared__ float tile[32][256];
  const int wsel = blockIdx.x;
  const float *W = (wsel == 0) ? Wq : (wsel == 1) ? Wk : Wv;
  const int t = threadIdx.x;
  for (int hb = 0; hb < 8; ++hb) {   // hb == kc chunk of 32 h-rows
    __syncthreads();
    #pragma unroll
    for (int p = 0; p < 8; ++p) {
      int r = p * 4 + (t >> 6);
      int c = (t & 63) * 4;
      *(floatx4 *)&tile[r][c] = *(const floatx4 *)&W[(hb * 32 + r) * HID + c];
    }
    __syncthreads();
    #pragma unroll
    for (int i = 0; i < 4; ++i) {    // 1024 (ct,lane) chunks
      const int c = i * 256 + t;
      const int lane_f = c & 63;
      const int ct = c >> 6;
      const int qf = lane_f >> 4;
      const int lnf = lane_f & 15;
      bf16x8 hh, ll;
      #pragma unroll
      for (int j = 0; j < 8; ++j) {
        float v = tile[qf * 8 + j][ct * 16 + lnf];
        __bf16 h, l;
        split_bf16(v, h, l);
        hh[j] = h; ll[j] = l;
      }
      const size_t dst = ((size_t)(wsel * 16 + ct) * 8 + hb) * 512 + lane_f * 8;
      *(bf16x8 *)&Whf[dst] = hh;
      *(bf16x8 *)&Wlf[dst] = ll;
    }
  }
}

// ---------------------------------------------------------------------------
// Kernel 2: QKV projection. W B-frags coalesced direct from global (L2-hot,
// frag-linear). LDS = 18.4 KB epilogue transpose scratch only.
// grid = (256 m-tiles of 64 tokens, 4 col-tiles of 64), 256 thr, 3 blocks/CU.
// ---------------------------------------------------------------------------
__global__ __launch_bounds__(256, 3) void qkv_proj(const float *__restrict__ X,
                                                   const __bf16 *__restrict__ Whf,
                                                   const __bf16 *__restrict__ Wlf,
                                                   __bf16 *__restrict__ Qh, __bf16 *__restrict__ Ql,
                                                   __bf16 *__restrict__ Kf,
                                                   __bf16 *__restrict__ Vf) {
  __shared__ __bf16 scr[2][64 * 72];  // Th=scr[0], Tl=scr[1]; Tv aliases scr[0]

  const int mtile = blockIdx.x;
  const int col0 = blockIdx.y * 64;
  const int tid = threadIdx.x;
  const int w4 = tid >> 6;
  const int lane = tid & 63;
  const int quad = lane >> 4;
  const int ln = lane & 15;
  const int arow = mtile * 64 + w4 * 16 + ln;

  // A-frags once: 8 k-chunks of X row, hi/lo split.
  bf16x8 ah[8], al[8];
  #pragma unroll
  for (int kc = 0; kc < 8; ++kc) {
    const float *xp = X + (size_t)arow * HID + kc * 32 + quad * 8;
    floatx4 x0 = *(const floatx4 *)xp;
    floatx4 x1 = *(const floatx4 *)(xp + 4);
    #pragma unroll
    for (int j = 0; j < 4; ++j) {
      __bf16 h, l;
      split_bf16(x0[j], h, l); ah[kc][j] = h; al[kc][j] = l;
      split_bf16(x1[j], h, l); ah[kc][4 + j] = h; al[kc][4 + j] = l;
    }
  }

  for (int w = 0; w < 3; ++w) {
    floatx4 acc[4] = {};
    #pragma unroll
    for (int kc = 0; kc < 8; ++kc) {
      #pragma unroll
      for (int nt = 0; nt < 4; ++nt) {
        const size_t wo = ((size_t)(w * 16 + (col0 >> 4) + nt) * 8 + kc) * 512 + lane * 8;
        bf16x8 bh = *(const bf16x8 *)&Whf[wo];
        bf16x8 bl = *(const bf16x8 *)&Wlf[wo];
        acc[nt] = MFMA16(ah[kc], bh, acc[nt]);
        acc[nt] = MFMA16(ah[kc], bl, acc[nt]);
        acc[nt] = MFMA16(al[kc], bh, acc[nt]);
      }
    }

    // Epilogues. C/D layout: col = lane&15, row = quad*4 + reg.
    if (w == 0) {
      #pragma unroll
      for (int nt = 0; nt < 4; ++nt) {
        #pragma unroll
        for (int r = 0; r < 4; ++r) {
          float v = acc[nt][r] * QSCALE;
          __bf16 h, l;
          split_bf16(v, h, l);
          const int orow = mtile * 64 + w4 * 16 + quad * 4 + r;
          const int ocol = col0 + nt * 16 + ln;
          Qh[(size_t)orow * HID + ocol] = h;
          Ql[(size_t)orow * HID + ocol] = l;
        }
      }
    } else if (w == 1) {
      #pragma unroll
      for (int nt = 0; nt < 4; ++nt) {
        #pragma unroll
        for (int r = 0; r < 4; ++r) {
          __bf16 h, l;
          split_bf16(acc[nt][r], h, l);
          const int tok_l = w4 * 16 + quad * 4 + r;
          const int h_l = nt * 16 + ln;
          scr[0][tok_l * 72 + h_l] = h;
          scr[1][tok_l * 72 + h_l] = l;
        }
      }
      __syncthreads();
      #pragma unroll
      for (int i = 0; i < 2; ++i) {     // 512 chunks
        const int c = i * 256 + tid;
        const int lane_f = c & 63;
        const int ntf = (c >> 6) & 1;
        const int kcL = (c >> 7) & 1;
        const int t2 = (c >> 8) & 1;
        const int qf = lane_f >> 4;
        const int lnf = lane_f & 15;
        const int tok_l = t2 * 32 + ntf * 16 + lnf;
        bf16x8 vh = *(const bf16x8 *)&scr[0][tok_l * 72 + kcL * 32 + qf * 8];
        bf16x8 vl = *(const bf16x8 *)&scr[1][tok_l * 72 + kcL * 32 + qf * 8];
        const int T = mtile * 2 + t2;
        const int kc = (col0 >> 5) + kcL;
        const size_t dst = (size_t)T * 16384 + ((ntf * 8 + kc) * 64 + lane_f) * 8;
        *(bf16x8 *)&Kf[dst] = vh;
        *(bf16x8 *)&Kf[dst + 8192] = vl;
      }
    } else {
      __syncthreads();  // w==1 scratch reads done before clobber
      #pragma unroll
      for (int nt = 0; nt < 4; ++nt) {
        #pragma unroll
        for (int r = 0; r < 4; ++r) {
          const int tok_l = w4 * 16 + quad * 4 + r;
          const int d_l = nt * 16 + ln;
          scr[0][d_l * 72 + tok_l] = (__bf16)acc[nt][r];
        }
      }
      __syncthreads();
      #pragma unroll
      for (int i = 0; i < 2; ++i) {     // 512 chunks
        const int c = i * 256 + tid;
        const int lane_f = c & 63;
        const int dtL = (c >> 6) & 3;
        const int t2 = (c >> 8) & 1;
        const int qf = lane_f >> 4;
        const int lnf = lane_f & 15;
        const int d_l = dtL * 16 + lnf;
        bf16x8 v = *(const bf16x8 *)&scr[0][d_l * 72 + t2 * 32 + qf * 8];
        const int T = mtile * 2 + t2;
        const int dt = (col0 >> 4) + dtL;
        *(bf16x8 *)&Vf[(size_t)(T * 16 + dt) * 512 + lane_f * 8] = v;
      }
    }
  }
}

// ---------------------------------------------------------------------------
// Kernel 3: flash attention. grid = 512 (qt = bx>>1, ks = bx&1), 256 thr,
// 2 blocks/CU. K dbuf staged by global_load_lds DMA (drains at the per-iter
// barrier); V direct from global; DPP softmax; 3-way QK chain split;
// alpha-skip O-rescale; P round-trip via per-wave LDS.
// ---------------------------------------------------------------------------
__global__ __launch_bounds__(256, 2) void attn(const __bf16 *__restrict__ QhG,
                                               const __bf16 *__restrict__ QlG,
                                               const __bf16 *__restrict__ Kf,
                                               const __bf16 *__restrict__ Vf,
                                               __bf16 *__restrict__ Op,
                                               float *__restrict__ Mp,
                                               float *__restrict__ Lp) {
  __shared__ __bf16 KS[2][16384];
  __shared__ __bf16 PsS[4 * 16 * 40];

  const int bx = blockIdx.x;
  const int ks = bx & 1;
  const int qt = bx >> 1;
  const int b = qt >> 6;
  const int qtl = qt & 63;
  const int tid = threadIdx.x;
  const int w4 = tid >> 6;
  const int lane = tid & 63;
  const int quad = lane >> 4;
  const int ln = lane & 15;
  const int T0 = b * 128 + ks * 64;

  const int qtok = b * LSEQ + qtl * 64 + w4 * 16 + ln;
  bf16x8 qh[8], ql[8];
  #pragma unroll
  for (int kc = 0; kc < 8; ++kc) {
    const size_t off = (size_t)qtok * HID + kc * 32 + quad * 8;
    qh[kc] = *(const bf16x8 *)&QhG[off];
    ql[kc] = *(const bf16x8 *)&QlG[off];
  }

  // Per-lane DMA source (lane*16B within each 1KB chunk; chunk = i*2048 el).
  const __bf16 *kdma = Kf + (size_t)T0 * 16384 + w4 * 512 + lane * 8;
  const __bf16 *vbase = Vf + (size_t)T0 * 8192 + lane * 8;

  // Prologue: DMA tile 0 -> KS[0].
  #pragma unroll
  for (int i = 0; i < 8; ++i)
    GLOAD_LDS16(kdma + i * 2048, &KS[0][i * 2048 + w4 * 512]);

  float m[4] = {-1e30f, -1e30f, -1e30f, -1e30f};
  float l[4] = {0.f, 0.f, 0.f, 0.f};
  floatx4 o[16] = {};

  for (int kt = 0; kt < 64; ++kt) {
    __syncthreads();  // vmcnt(0) drain: DMA for KS[kt&1] complete; prior reads done

    // DMA next tile -> other buffer (its readers finished before this barrier).
    if (kt < 63) {
      const __bf16 *src = kdma + (size_t)(kt + 1) * 16384;
      __bf16 *dstb = KS[(kt + 1) & 1];
      #pragma unroll
      for (int i = 0; i < 8; ++i)
        GLOAD_LDS16(src + i * 2048, &dstb[i * 2048 + w4 * 512]);
    }

    const __bf16 *buf = KS[kt & 1];
    const __bf16 *vsrc = vbase + (size_t)kt * 8192;
    bf16x8 vb0[8];
    #pragma unroll
    for (int dt = 0; dt < 8; ++dt) vb0[dt] = *(const bf16x8 *)&vsrc[dt * 512];

    // ---- S = Q K^T : 3 independent 8-deep MFMA chains per nt ----
    floatx4 shh[2] = {}, shl[2] = {}, slh[2] = {};
    #pragma unroll
    for (int nt = 0; nt < 2; ++nt) {
      #pragma unroll
      for (int kc = 0; kc < 8; ++kc) {
        const __bf16 *kp = buf + (nt * 8 + kc) * 512 + lane * 8;
        bf16x8 bh = *(const bf16x8 *)kp;
        bf16x8 bl = *(const bf16x8 *)(kp + 8192);
        shh[nt] = MFMA16(qh[kc], bh, shh[nt]);
        shl[nt] = MFMA16(qh[kc], bl, shl[nt]);
        slh[nt] = MFMA16(ql[kc], bh, slh[nt]);
      }
    }
    floatx4 s[2];
    s[0] = (shl[0] + slh[0]) + shh[0];
    s[1] = (shl[1] + slh[1]) + shh[1];

    bf16x8 vb1[8];
    #pragma unroll
    for (int dt = 0; dt < 8; ++dt) vb1[dt] = *(const bf16x8 *)&vsrc[(8 + dt) * 512];

    // ---- online softmax (base-2), DPP 16-lane-row reductions ----
    float alpha[4];
    #pragma unroll
    for (int r = 0; r < 4; ++r) {
      const float tmax = row_max16(fmaxf(s[0][r], s[1][r]));
      const float mn = fmaxf(m[r], tmax);
      const float al = exp2f(m[r] - mn);
      const float p0 = exp2f(s[0][r] - mn);
      const float p1 = exp2f(s[1][r] - mn);
      s[0][r] = p0; s[1][r] = p1;
      const float rs = row_sum16(p0 + p1);
      l[r] = l[r] * al + rs;
      m[r] = mn;
      alpha[r] = al;
    }

    // ---- P write (C-layout -> A-layout via per-wave LDS) ----
    __bf16 *ps = PsS + w4 * 16 * 40;
    #pragma unroll
    for (int nt = 0; nt < 2; ++nt)
      #pragma unroll
      for (int r = 0; r < 4; ++r)
        ps[(quad * 4 + r) * 40 + nt * 16 + ln] = (__bf16)s[nt][r];

    // ---- O rescale only when some row's max moved (wave-uniform branch;
    //      near-one-hot logits -> skipped on ~94% of iters) ----
    const float amin = fminf(fminf(alpha[0], alpha[1]), fminf(alpha[2], alpha[3]));
    if (__any(amin < 1.0f)) {
      #pragma unroll
      for (int dt = 0; dt < 16; ++dt) {
        o[dt][0] *= alpha[0]; o[dt][1] *= alpha[1];
        o[dt][2] *= alpha[2]; o[dt][3] *= alpha[3];
      }
    }

    const bf16x8 pa = *(const bf16x8 *)&ps[ln * 40 + quad * 8];

    // ---- O += P V ----
    #pragma unroll
    for (int dt = 0; dt < 8; ++dt) o[dt] = MFMA16(pa, vb0[dt], o[dt]);
    #pragma unroll
    for (int dt = 0; dt < 8; ++dt) o[8 + dt] = MFMA16(pa, vb1[dt], o[8 + dt]);
  }

  const int rowbase = b * LSEQ + qtl * 64 + w4 * 16 + quad * 4;
  #pragma unroll
  for (int dt = 0; dt < 16; ++dt)
    #pragma unroll
    for (int r = 0; r < 4; ++r)
      Op[(size_t)ks * PLANE + (size_t)(rowbase + r) * HID + dt * 16 + ln] = (__bf16)o[dt][r];
  if (ln == 0) {
    #pragma unroll
    for (int r = 0; r < 4; ++r) {
      Mp[ks * NTOK + rowbase + r] = m[r];
      Lp[ks * NTOK + rowbase + r] = l[r];
    }
  }
}

// ---------------------------------------------------------------------------
// Kernel 4: split-K merge.
// ---------------------------------------------------------------------------
__global__ __launch_bounds__(256) void merge(const __bf16 *__restrict__ Op,
                                             const float *__restrict__ Mp,
                                             const float *__restrict__ Lp,
                                             float *__restrict__ Out) {
  const int row = blockIdx.x * 4 + (threadIdx.x >> 6);
  const int c = (threadIdx.x & 63) * 4;
  const float m0 = Mp[row], m1 = Mp[NTOK + row];
  const float l0 = Lp[row], l1 = Lp[NTOK + row];
  const float M = fmaxf(m0, m1);
  const float e0 = exp2f(m0 - M), e1 = exp2f(m1 - M);
  const float invL = 1.0f / (l0 * e0 + l1 * e1);
  const float w0 = e0 * invL, w1 = e1 * invL;
  bf16x4 a = *(const bf16x4 *)&Op[(size_t)row * HID + c];
  bf16x4 b4 = *(const bf16x4 *)&Op[PLANE + (size_t)row * HID + c];
  floatx4 out;
  #pragma unroll
  for (int i = 0; i < 4; ++i) out[i] = w0 * (float)a[i] + w1 * (float)b4[i];
  *(floatx4 *)&Out[(size_t)row * HID + c] = out;
}

// ---------------------------------------------------------------------------
extern "C" void kernel_launch(void *const *d_in, const int *in_sizes, int n_in,
                              void *d_out, int out_size, void *d_ws, size_t ws_size,
                              hipStream_t stream) {
  const float *X = (const float *)d_in[0];
  const float *Wq = (const float *)d_in[1];
  const float *Wk = (const float *)d_in[2];
  const float *Wv = (const float *)d_in[3];
  // d_in[4] = lengths (unused by reference)

  const size_t WFRAG = (size_t)3 * 16 * 8 * 512;  // 196608 el per plane

  __bf16 *ws = (__bf16 *)d_ws;
  __bf16 *Qh = ws;                           // [16384][256] row-major
  __bf16 *Ql = Qh + PLANE;
  __bf16 *Kf = Ql + PLANE;                   // 32-key frag-linear, 2*PLANE (hi+lo)
  __bf16 *Vf = Kf + 2 * PLANE;               // 32-key frag-linear, PLANE
  __bf16 *Whf = Vf + PLANE;                  // frag-linear weights
  __bf16 *Wlf = Whf + WFRAG;
  __bf16 *Op = Wlf + WFRAG;                  // [2][16384][256] unnormalized
  float *Mp = (float *)(Op + 2 * PLANE);     // [2][16384]
  float *Lp = Mp + 2 * NTOK;                 // [2][16384]

  wsplit<<<3, 256, 0, stream>>>(Wq, Wk, Wv, Whf, Wlf);
  qkv_proj<<<dim3(256, 4), 256, 0, stream>>>(X, Whf, Wlf, Qh, Ql, Kf, Vf);
  attn<<<512, 256, 0, stream>>>(Qh, Ql, Kf, Vf, Op, Mp, Lp);
  merge<<<NTOK / 4, 256, 0, stream>>>(Op, Mp, Lp, (float *)d_out);
}

// Round 8
// 272.517 us; speedup vs baseline: 1.2269x; 1.2269x over previous
//
#include <hip/hip_runtime.h>

// SelfAttention: B=4, L=4096, H=256, fp32 in/out.
// Round 8: qkv reverted to r6 LDS-staged W (r7's direct-global W was L2-latency
// bound: 256 KB/phase >> 32 KB L1) + W reg-prefetch dbuf. attn keeps r7's DMA
// dbuf + DPP + alpha-skip and adds: uniform-base addressing (V loads + K DMA
// keep lane offset in a fixed VGPR, bases on SALU) and a 64-key macro softmax
// (one max/alpha/m/l/P-round-trip per 64 keys; barrier count unchanged).
// Structural: 2 blocks/CU is the max (live set ~200 regs, LDS 73 KB; r5 proved
// the 3-block spill). wsplit parallelized to grid (3,8).
// Precision: split-bf16 3-product QK (fp32-accurate logits; logits O(1e3+) with
// near-tie rows), bf16 PV, bf16 O-partials. Measured absmax 0.25 @ 1.01.

typedef __bf16 bf16x8 __attribute__((ext_vector_type(8)));
typedef __bf16 bf16x4 __attribute__((ext_vector_type(4)));
typedef float floatx4 __attribute__((ext_vector_type(4)));

#define MFMA16(a, b, c) __builtin_amdgcn_mfma_f32_16x16x32_bf16(a, b, c, 0, 0, 0)
#define GLOAD_LDS16(g, l)                                                  \
  __builtin_amdgcn_global_load_lds(                                        \
      (const __attribute__((address_space(1))) void *)(g),                 \
      (__attribute__((address_space(3))) void *)(l), 16, 0, 0)

#define HID 256
#define LSEQ 4096
#define NB 4
#define NTOK (NB * LSEQ)             // 16384
#define PLANE ((size_t)NTOK * HID)   // 4,194,304 elements
#define QSCALE 0.09016844005556021f  // log2(e)/16 ; softmax uses exp2

// Layouts:
//  Wht/Wlt [3][n][h] row-major hi/lo bf16 weights (transposed).
//  Kf (32-key tiles, T = tok>>5, 512 tiles): [T][hi/lo][nt(2)][kc(8)][lane][j],
//    tile stride 16384 el (hi 0..8191, lo +8192).
//  Vf (32-key tiles): [T][dt(16)][lane][j], tile stride 8192 el.

__device__ __forceinline__ void split_bf16(float v, __bf16 &h, __bf16 &l) {
  h = (__bf16)v;
  l = (__bf16)(v - (float)h);
}

// DPP 16-lane-row butterfly reductions (VALU, no LDS pipe).
template <int N>
__device__ __forceinline__ float dpp_ror(float v) {
  return __builtin_bit_cast(float,
      __builtin_amdgcn_update_dpp(0, __builtin_bit_cast(int, v),
                                  0x120 + N, 0xf, 0xf, true));
}
__device__ __forceinline__ float row_sum16(float v) {
  v += dpp_ror<1>(v);
  v += dpp_ror<2>(v);
  v += dpp_ror<4>(v);
  v += dpp_ror<8>(v);
  return v;
}
__device__ __forceinline__ float row_max16(float v) {
  v = fmaxf(v, dpp_ror<1>(v));
  v = fmaxf(v, dpp_ror<2>(v));
  v = fmaxf(v, dpp_ror<4>(v));
  v = fmaxf(v, dpp_ror<8>(v));
  return v;
}

// ---------------------------------------------------------------------------
// Kernel 1: transpose + hi/lo-split weights -> Wht/Wlt [3][n][h] row-major.
// grid (3, 8): one 32-h-row slab per block (was a serial 8-slab loop on 3 CUs).
// ---------------------------------------------------------------------------
__global__ __launch_bounds__(256) void wsplit(const float *__restrict__ Wq,
                                              const float *__restrict__ Wk,
                                              const float *__restrict__ Wv,
                                              __bf16 *__restrict__ Wht,
                                              __bf16 *__restrict__ Wlt) {
  __shared__ float tile[32][256];
  const int wsel = blockIdx.x;
  const int hb = blockIdx.y;
  const float *W = (wsel == 0) ? Wq : (wsel == 1) ? Wk : Wv;
  __bf16 *oh = Wht + wsel * HID * HID;
  __bf16 *ol = Wlt + wsel * HID * HID;
  const int t = threadIdx.x;
  #pragma unroll
  for (int p = 0; p < 8; ++p) {
    int r = p * 4 + (t >> 6);
    int c = (t & 63) * 4;
    *(floatx4 *)&tile[r][c] = *(const floatx4 *)&W[(hb * 32 + r) * HID + c];
  }
  __syncthreads();
  #pragma unroll
  for (int q = 0; q < 4; ++q) {
    int n = q * 64 + (t >> 2);
    int hs = (t & 3) * 8;
    bf16x8 hh, ll;
    #pragma unroll
    for (int i = 0; i < 8; ++i) {
      float v = tile[hs + i][n];
      __bf16 h, l;
      split_bf16(v, h, l);
      hh[i] = h; ll[i] = l;
    }
    *(bf16x8 *)&oh[n * HID + hb * 32 + hs] = hh;
    *(bf16x8 *)&ol[n * HID + hb * 32 + hs] = ll;
  }
}

// ---------------------------------------------------------------------------
// Kernel 2: QKV projection (r6 structure). W tiles staged in LDS (xor-swizzle)
// with next-phase chunks prefetched into registers during the current MFMA
// loop; A-frags in regs. Epilogues: Q row-major hi/lo; K,V -> fragment-linear.
// grid = (256 m-tiles, 4 col-tiles), 256 thr, 2 blocks/CU.
// ---------------------------------------------------------------------------
__global__ __launch_bounds__(256, 2) void qkv_proj(const float *__restrict__ X,
                                                   const __bf16 *__restrict__ Wht,
                                                   const __bf16 *__restrict__ Wlt,
                                                   __bf16 *__restrict__ Qh, __bf16 *__restrict__ Ql,
                                                   __bf16 *__restrict__ Kf,
                                                   __bf16 *__restrict__ Vf) {
  __shared__ __bf16 WhS[64 * 256];
  __shared__ __bf16 WlS[64 * 256];
  __bf16 *Th = WhS;            // 64 x 72 scratch (aliases WhS, barrier-bracketed)
  __bf16 *Tl = WhS + 64 * 72;
  __bf16 *Tv = WhS;

  const int mtile = blockIdx.x;
  const int col0 = blockIdx.y * 64;
  const int tid = threadIdx.x;
  const int w4 = tid >> 6;
  const int lane = tid & 63;
  const int quad = lane >> 4;
  const int ln = lane & 15;
  const int arow = mtile * 64 + w4 * 16 + ln;

  bf16x8 ah[8], al[8];
  #pragma unroll
  for (int kc = 0; kc < 8; ++kc) {
    const float *xp = X + (size_t)arow * HID + kc * 32 + quad * 8;
    floatx4 x0 = *(const floatx4 *)xp;
    floatx4 x1 = *(const floatx4 *)(xp + 4);
    #pragma unroll
    for (int j = 0; j < 4; ++j) {
      __bf16 h, l;
      split_bf16(x0[j], h, l); ah[kc][j] = h; al[kc][j] = l;
      split_bf16(x1[j], h, l); ah[kc][4 + j] = h; al[kc][4 + j] = l;
    }
  }

  const int srow = tid >> 2;
  const int sseg = tid & 3;

  // Prefetch phase-0 W chunks into registers.
  bf16x8 pwh[8], pwl[8];
  {
    const size_t wbase = (size_t)(col0 + srow) * HID;
    #pragma unroll
    for (int j = 0; j < 8; ++j) {
      const int chunk = j * 4 + sseg;
      pwh[j] = *(const bf16x8 *)&Wht[wbase + chunk * 8];
      pwl[j] = *(const bf16x8 *)&Wlt[wbase + chunk * 8];
    }
  }

  for (int w = 0; w < 3; ++w) {
    __syncthreads();  // W region free (prev MFMA reads / scratch reads done)
    #pragma unroll
    for (int j = 0; j < 8; ++j) {
      const int chunk = j * 4 + sseg;
      const int dst = srow * 256 + ((chunk ^ (srow & 7)) << 3);
      *(bf16x8 *)&WhS[dst] = pwh[j];
      *(bf16x8 *)&WlS[dst] = pwl[j];
    }
    __syncthreads();

    // Prefetch next phase's W chunks (global latency hidden under MFMA).
    if (w < 2) {
      const size_t wbase = (size_t)(w + 1) * HID * HID + (size_t)(col0 + srow) * HID;
      #pragma unroll
      for (int j = 0; j < 8; ++j) {
        const int chunk = j * 4 + sseg;
        pwh[j] = *(const bf16x8 *)&Wht[wbase + chunk * 8];
        pwl[j] = *(const bf16x8 *)&Wlt[wbase + chunk * 8];
      }
    }

    floatx4 acc[4] = {};
    #pragma unroll
    for (int kc = 0; kc < 8; ++kc) {
      #pragma unroll
      for (int nt = 0; nt < 4; ++nt) {
        const int a = (nt * 16 + ln) * 256 + (((kc * 4 + quad) ^ (ln & 7)) << 3);
        bf16x8 bh = *(const bf16x8 *)&WhS[a];
        bf16x8 bl = *(const bf16x8 *)&WlS[a];
        acc[nt] = MFMA16(ah[kc], bh, acc[nt]);
        acc[nt] = MFMA16(ah[kc], bl, acc[nt]);
        acc[nt] = MFMA16(al[kc], bh, acc[nt]);
      }
    }

    // Epilogues. C/D layout: col = lane&15, row = quad*4 + reg.
    if (w == 0) {
      #pragma unroll
      for (int nt = 0; nt < 4; ++nt) {
        #pragma unroll
        for (int r = 0; r < 4; ++r) {
          float v = acc[nt][r] * QSCALE;
          __bf16 h, l;
          split_bf16(v, h, l);
          const int orow = mtile * 64 + w4 * 16 + quad * 4 + r;
          const int ocol = col0 + nt * 16 + ln;
          Qh[(size_t)orow * HID + ocol] = h;
          Ql[(size_t)orow * HID + ocol] = l;
        }
      }
    } else if (w == 1) {
      __syncthreads();  // all MFMA reads of WhS done before scratch clobber
      #pragma unroll
      for (int nt = 0; nt < 4; ++nt) {
        #pragma unroll
        for (int r = 0; r < 4; ++r) {
          __bf16 h, l;
          split_bf16(acc[nt][r], h, l);
          const int tok_l = w4 * 16 + quad * 4 + r;
          const int h_l = nt * 16 + ln;
          Th[tok_l * 72 + h_l] = h;
          Tl[tok_l * 72 + h_l] = l;
        }
      }
      __syncthreads();
      #pragma unroll
      for (int i = 0; i < 2; ++i) {
        const int c = i * 256 + tid;
        const int lane_f = c & 63;
        const int ntf = (c >> 6) & 1;
        const int kcL = (c >> 7) & 1;
        const int t2 = (c >> 8) & 1;
        const int qf = lane_f >> 4;
        const int lnf = lane_f & 15;
        const int tok_l = t2 * 32 + ntf * 16 + lnf;
        bf16x8 vh = *(const bf16x8 *)&Th[tok_l * 72 + kcL * 32 + qf * 8];
        bf16x8 vl = *(const bf16x8 *)&Tl[tok_l * 72 + kcL * 32 + qf * 8];
        const int T = mtile * 2 + t2;
        const int kc = (col0 >> 5) + kcL;
        const size_t dst = (size_t)T * 16384 + ((ntf * 8 + kc) * 64 + lane_f) * 8;
        *(bf16x8 *)&Kf[dst] = vh;
        *(bf16x8 *)&Kf[dst + 8192] = vl;
      }
    } else {
      __syncthreads();
      #pragma unroll
      for (int nt = 0; nt < 4; ++nt) {
        #pragma unroll
        for (int r = 0; r < 4; ++r) {
          const int tok_l = w4 * 16 + quad * 4 + r;
          const int d_l = nt * 16 + ln;
          Tv[d_l * 72 + tok_l] = (__bf16)acc[nt][r];
        }
      }
      __syncthreads();
      #pragma unroll
      for (int i = 0; i < 2; ++i) {
        const int c = i * 256 + tid;
        const int lane_f = c & 63;
        const int dtL = (c >> 6) & 3;
        const int t2 = (c >> 8) & 1;
        const int qf = lane_f >> 4;
        const int lnf = lane_f & 15;
        const int d_l = dtL * 16 + lnf;
        bf16x8 v = *(const bf16x8 *)&Tv[d_l * 72 + t2 * 32 + qf * 8];
        const int T = mtile * 2 + t2;
        const int dt = (col0 >> 4) + dtL;
        *(bf16x8 *)&Vf[(size_t)(T * 16 + dt) * 512 + lane_f * 8] = v;
      }
    }
  }
}

// ---------------------------------------------------------------------------
// Kernel 3: flash attention. grid = 512 (qt = bx>>1, ks = bx&1), 256 thr,
// 2 blocks/CU (LDS 73 KB). Per 64-key macro-iter: DMA-dbuf KS0/KS1 (one
// barrier per 32-key tile, unchanged), QK on both tiles, ONE softmax/rescale/
// P-round-trip. V direct from global with uniform bases; DPP reductions;
// 3-way QK chain split; alpha-skip rescale.
// ---------------------------------------------------------------------------
__global__ __launch_bounds__(256, 2) void attn(const __bf16 *__restrict__ QhG,
                                               const __bf16 *__restrict__ QlG,
                                               const __bf16 *__restrict__ Kf,
                                               const __bf16 *__restrict__ Vf,
                                               __bf16 *__restrict__ Op,
                                               float *__restrict__ Mp,
                                               float *__restrict__ Lp) {
  __shared__ __bf16 KS0[16384];
  __shared__ __bf16 KS1[16384];
  __shared__ __bf16 PsS[4 * 16 * 72];

  const int bx = blockIdx.x;
  const int ks = bx & 1;
  const int qt = bx >> 1;
  const int b = qt >> 6;
  const int qtl = qt & 63;
  const int tid = threadIdx.x;
  const int w4 = tid >> 6;
  const int lane = tid & 63;
  const int quad = lane >> 4;
  const int ln = lane & 15;
  const int T0 = b * 128 + ks * 64;

  const int qtok = b * LSEQ + qtl * 64 + w4 * 16 + ln;
  bf16x8 qh[8], ql[8];
  #pragma unroll
  for (int kc = 0; kc < 8; ++kc) {
    const size_t off = (size_t)qtok * HID + kc * 32 + quad * 8;
    qh[kc] = *(const bf16x8 *)&QhG[off];
    ql[kc] = *(const bf16x8 *)&QlG[off];
  }

  // Uniform bases (SALU) + fixed per-lane offsets (one VGPR each).
  const __bf16 *kuni = Kf + (size_t)T0 * 16384;
  const __bf16 *vuni = Vf + (size_t)T0 * 8192;
  const int koff = w4 * 512 + lane * 8;
  const int loff = w4 * 512;
  const int voff = lane * 8;

  // Prologue: DMA tile 0 -> KS0.
  #pragma unroll
  for (int i = 0; i < 8; ++i)
    GLOAD_LDS16(kuni + i * 2048 + koff, &KS0[i * 2048 + loff]);

  float m[4] = {-1e30f, -1e30f, -1e30f, -1e30f};
  float l[4] = {0.f, 0.f, 0.f, 0.f};
  floatx4 o[16] = {};

  for (int jm = 0; jm < 32; ++jm) {
    floatx4 s[4];
    // ---------- tile A (keys 64*jm..+31) from KS0 ----------
    __syncthreads();  // drains KS0's DMA; all waves done reading KS1 (prev macro)
    {
      const __bf16 *src = kuni + (size_t)(2 * jm + 1) * 16384 + koff;
      #pragma unroll
      for (int i = 0; i < 8; ++i)
        GLOAD_LDS16(src + i * 2048, &KS1[i * 2048 + loff]);
    }
    {
      floatx4 shh[2] = {}, shl[2] = {}, slh[2] = {};
      #pragma unroll
      for (int nt = 0; nt < 2; ++nt)
        #pragma unroll
        for (int kc = 0; kc < 8; ++kc) {
          const __bf16 *kp = KS0 + (nt * 8 + kc) * 512 + voff;
          bf16x8 bh = *(const bf16x8 *)kp;
          bf16x8 bl = *(const bf16x8 *)(kp + 8192);
          shh[nt] = MFMA16(qh[kc], bh, shh[nt]);
          shl[nt] = MFMA16(qh[kc], bl, shl[nt]);
          slh[nt] = MFMA16(ql[kc], bh, slh[nt]);
        }
      s[0] = (shl[0] + slh[0]) + shh[0];
      s[1] = (shl[1] + slh[1]) + shh[1];
    }
    // ---------- tile B (keys +32..+63) from KS1 ----------
    __syncthreads();  // drains KS1's DMA; all waves done reading KS0
    if (jm < 31) {
      const __bf16 *src = kuni + (size_t)(2 * jm + 2) * 16384 + koff;
      #pragma unroll
      for (int i = 0; i < 8; ++i)
        GLOAD_LDS16(src + i * 2048, &KS0[i * 2048 + loff]);
    }
    const __bf16 *va = vuni + (size_t)(2 * jm) * 8192;
    const __bf16 *vbp = vuni + (size_t)(2 * jm + 1) * 8192;
    bf16x8 vb0[8];
    #pragma unroll
    for (int dt = 0; dt < 8; ++dt)
      vb0[dt] = *(const bf16x8 *)(va + dt * 512 + voff);
    {
      floatx4 shh[2] = {}, shl[2] = {}, slh[2] = {};
      #pragma unroll
      for (int nt = 0; nt < 2; ++nt)
        #pragma unroll
        for (int kc = 0; kc < 8; ++kc) {
          const __bf16 *kp = KS1 + (nt * 8 + kc) * 512 + voff;
          bf16x8 bh = *(const bf16x8 *)kp;
          bf16x8 bl = *(const bf16x8 *)(kp + 8192);
          shh[nt] = MFMA16(qh[kc], bh, shh[nt]);
          shl[nt] = MFMA16(qh[kc], bl, shl[nt]);
          slh[nt] = MFMA16(ql[kc], bh, slh[nt]);
        }
      s[2] = (shl[0] + slh[0]) + shh[0];
      s[3] = (shl[1] + slh[1]) + shh[1];
    }
    bf16x8 vb1[8];
    #pragma unroll
    for (int dt = 0; dt < 8; ++dt)
      vb1[dt] = *(const bf16x8 *)(va + (8 + dt) * 512 + voff);

    // ---------- softmax over 64 keys (base-2, DPP) ----------
    float alpha[4];
    #pragma unroll
    for (int r = 0; r < 4; ++r) {
      const float tmax = row_max16(
          fmaxf(fmaxf(s[0][r], s[1][r]), fmaxf(s[2][r], s[3][r])));
      const float mn = fmaxf(m[r], tmax);
      const float al = exp2f(m[r] - mn);
      const float p0 = exp2f(s[0][r] - mn);
      const float p1 = exp2f(s[1][r] - mn);
      const float p2 = exp2f(s[2][r] - mn);
      const float p3 = exp2f(s[3][r] - mn);
      s[0][r] = p0; s[1][r] = p1; s[2][r] = p2; s[3][r] = p3;
      const float rs = row_sum16((p0 + p1) + (p2 + p3));
      l[r] = l[r] * al + rs;
      m[r] = mn;
      alpha[r] = al;
    }

    // ---------- P write (C-layout -> A-layout via per-wave LDS) ----------
    __bf16 *ps = PsS + w4 * 16 * 72;
    #pragma unroll
    for (int nt = 0; nt < 4; ++nt)
      #pragma unroll
      for (int r = 0; r < 4; ++r)
        ps[(quad * 4 + r) * 72 + nt * 16 + ln] = (__bf16)s[nt][r];

    // ---------- O rescale (alpha-skip; near-one-hot -> mostly skipped) ------
    const float amin = fminf(fminf(alpha[0], alpha[1]), fminf(alpha[2], alpha[3]));
    if (__any(amin < 1.0f)) {
      #pragma unroll
      for (int dt = 0; dt < 16; ++dt) {
        o[dt][0] *= alpha[0]; o[dt][1] *= alpha[1];
        o[dt][2] *= alpha[2]; o[dt][3] *= alpha[3];
      }
    }

    const bf16x8 paA = *(const bf16x8 *)&ps[ln * 72 + quad * 8];
    const bf16x8 paB = *(const bf16x8 *)&ps[ln * 72 + 32 + quad * 8];

    // ---------- O += P V (two 32-key halves) ----------
    #pragma unroll
    for (int dt = 0; dt < 8; ++dt) o[dt] = MFMA16(paA, vb0[dt], o[dt]);
    bf16x8 vb2[8];
    #pragma unroll
    for (int dt = 0; dt < 8; ++dt)
      vb2[dt] = *(const bf16x8 *)(vbp + dt * 512 + voff);
    #pragma unroll
    for (int dt = 0; dt < 8; ++dt) o[8 + dt] = MFMA16(paA, vb1[dt], o[8 + dt]);
    bf16x8 vb3[8];
    #pragma unroll
    for (int dt = 0; dt < 8; ++dt)
      vb3[dt] = *(const bf16x8 *)(vbp + (8 + dt) * 512 + voff);
    #pragma unroll
    for (int dt = 0; dt < 8; ++dt) o[dt] = MFMA16(paB, vb2[dt], o[dt]);
    #pragma unroll
    for (int dt = 0; dt < 8; ++dt) o[8 + dt] = MFMA16(paB, vb3[dt], o[8 + dt]);
  }

  const int rowbase = b * LSEQ + qtl * 64 + w4 * 16 + quad * 4;
  #pragma unroll
  for (int dt = 0; dt < 16; ++dt)
    #pragma unroll
    for (int r = 0; r < 4; ++r)
      Op[(size_t)ks * PLANE + (size_t)(rowbase + r) * HID + dt * 16 + ln] = (__bf16)o[dt][r];
  if (ln == 0) {
    #pragma unroll
    for (int r = 0; r < 4; ++r) {
      Mp[ks * NTOK + rowbase + r] = m[r];
      Lp[ks * NTOK + rowbase + r] = l[r];
    }
  }
}

// ---------------------------------------------------------------------------
// Kernel 4: split-K merge.
// ---------------------------------------------------------------------------
__global__ __launch_bounds__(256) void merge(const __bf16 *__restrict__ Op,
                                             const float *__restrict__ Mp,
                                             const float *__restrict__ Lp,
                                             float *__restrict__ Out) {
  const int row = blockIdx.x * 4 + (threadIdx.x >> 6);
  const int c = (threadIdx.x & 63) * 4;
  const float m0 = Mp[row], m1 = Mp[NTOK + row];
  const float l0 = Lp[row], l1 = Lp[NTOK + row];
  const float M = fmaxf(m0, m1);
  const float e0 = exp2f(m0 - M), e1 = exp2f(m1 - M);
  const float invL = 1.0f / (l0 * e0 + l1 * e1);
  const float w0 = e0 * invL, w1 = e1 * invL;
  bf16x4 a = *(const bf16x4 *)&Op[(size_t)row * HID + c];
  bf16x4 b4 = *(const bf16x4 *)&Op[PLANE + (size_t)row * HID + c];
  floatx4 out;
  #pragma unroll
  for (int i = 0; i < 4; ++i) out[i] = w0 * (float)a[i] + w1 * (float)b4[i];
  *(floatx4 *)&Out[(size_t)row * HID + c] = out;
}

// ---------------------------------------------------------------------------
extern "C" void kernel_launch(void *const *d_in, const int *in_sizes, int n_in,
                              void *d_out, int out_size, void *d_ws, size_t ws_size,
                              hipStream_t stream) {
  const float *X = (const float *)d_in[0];
  const float *Wq = (const float *)d_in[1];
  const float *Wk = (const float *)d_in[2];
  const float *Wv = (const float *)d_in[3];
  // d_in[4] = lengths (unused by reference)

  __bf16 *ws = (__bf16 *)d_ws;
  __bf16 *Qh = ws;                           // [16384][256] row-major
  __bf16 *Ql = Qh + PLANE;
  __bf16 *Kf = Ql + PLANE;                   // 32-key frag-linear, 2*PLANE (hi+lo)
  __bf16 *Vf = Kf + 2 * PLANE;               // 32-key frag-linear, PLANE
  __bf16 *Wht = Vf + PLANE;                  // [3][256][256]
  __bf16 *Wlt = Wht + 3 * HID * HID;
  __bf16 *Op = Wlt + 3 * HID * HID;          // [2][16384][256] unnormalized
  float *Mp = (float *)(Op + 2 * PLANE);     // [2][16384]
  float *Lp = Mp + 2 * NTOK;                 // [2][16384]

  wsplit<<<dim3(3, 8), 256, 0, stream>>>(Wq, Wk, Wv, Wht, Wlt);
  qkv_proj<<<dim3(256, 4), 256, 0, stream>>>(X, Wht, Wlt, Qh, Ql, Kf, Vf);
  attn<<<512, 256, 0, stream>>>(Qh, Ql, Kf, Vf, Op, Mp, Lp);
  merge<<<NTOK / 4, 256, 0, stream>>>(Op, Mp, Lp, (float *)d_out);
}

// Round 9
// 235.502 us; speedup vs baseline: 1.4198x; 1.1572x over previous
//
#include <hip/hip_runtime.h>

// SelfAttention: B=4, L=4096, H=256, fp32 in/out.
// Round 9: fp16 attention core. Q/K/V/P/O-partials are fp16 (11-bit mantissa):
// QK = ONE mfma_f32_16x16x32_f16 instead of 3-product split-bf16 (per-macro
// MFMA 128->64, attn MFMA floor 66->33 us; K tile 32->16 KB, DMA + ds_read
// halve, LDS 74->41 KB). Error arithmetic: logit rounding sigma ~0.03 natural
// units (fine vs near-tie gaps); P/O move bf16->fp16 which CUTS the previously
// dominant quantization error 0.25 -> ~0.06. qkv projections keep the accurate
// 3-product split-bf16 path; only the stored Q/K/V round to fp16.
// Carried from r8: DMA-dbuf K staging, DPP softmax, alpha-skip, uniform bases,
// 64-key macro softmax, (256,2) everywhere (r5 proved 3-block spills).

typedef __bf16 bf16x8 __attribute__((ext_vector_type(8)));
typedef _Float16 f16x8 __attribute__((ext_vector_type(8)));
typedef _Float16 f16x4 __attribute__((ext_vector_type(4)));
typedef float floatx4 __attribute__((ext_vector_type(4)));

#define MFMA16B(a, b, c) __builtin_amdgcn_mfma_f32_16x16x32_bf16(a, b, c, 0, 0, 0)
#define MFMA16F(a, b, c) __builtin_amdgcn_mfma_f32_16x16x32_f16(a, b, c, 0, 0, 0)
#define GLOAD_LDS16(g, l)                                                  \
  __builtin_amdgcn_global_load_lds(                                        \
      (const __attribute__((address_space(1))) void *)(g),                 \
      (__attribute__((address_space(3))) void *)(l), 16, 0, 0)

#define HID 256
#define LSEQ 4096
#define NB 4
#define NTOK (NB * LSEQ)             // 16384
#define PLANE ((size_t)NTOK * HID)   // 4,194,304 elements
#define QSCALE 0.09016844005556021f  // log2(e)/16 ; softmax uses exp2

// Layouts:
//  Wht/Wlt [3][n][h] row-major hi/lo bf16 weights (transposed).
//  Qf [tok][h] row-major fp16 (pre-scaled by QSCALE).
//  Kf (32-key tiles, T = tok>>5, 512 tiles): [T][nt(2)][kc(8)][lane(64)][j(8)]
//    fp16, tile stride 8192 el (16 KB).
//    element = K[key = T*32 + nt*16 + (lane&15)][h = kc*32 + (lane>>4)*8 + j]
//  Vf (32-key tiles): [T][dt(16)][lane][j] fp16, tile stride 8192 el.
//    element = V[key = T*32 + (lane>>4)*8 + j][d = dt*16 + (lane&15)]

__device__ __forceinline__ void split_bf16(float v, __bf16 &h, __bf16 &l) {
  h = (__bf16)v;
  l = (__bf16)(v - (float)h);
}

// DPP 16-lane-row butterfly reductions (VALU, no LDS pipe).
template <int N>
__device__ __forceinline__ float dpp_ror(float v) {
  return __builtin_bit_cast(float,
      __builtin_amdgcn_update_dpp(0, __builtin_bit_cast(int, v),
                                  0x120 + N, 0xf, 0xf, true));
}
__device__ __forceinline__ float row_sum16(float v) {
  v += dpp_ror<1>(v);
  v += dpp_ror<2>(v);
  v += dpp_ror<4>(v);
  v += dpp_ror<8>(v);
  return v;
}
__device__ __forceinline__ float row_max16(float v) {
  v = fmaxf(v, dpp_ror<1>(v));
  v = fmaxf(v, dpp_ror<2>(v));
  v = fmaxf(v, dpp_ror<4>(v));
  v = fmaxf(v, dpp_ror<8>(v));
  return v;
}

// ---------------------------------------------------------------------------
// Kernel 1: transpose + hi/lo-split weights -> Wht/Wlt [3][n][h] row-major.
// grid (3, 8): one 32-h-row slab per block.
// ---------------------------------------------------------------------------
__global__ __launch_bounds__(256) void wsplit(const float *__restrict__ Wq,
                                              const float *__restrict__ Wk,
                                              const float *__restrict__ Wv,
                                              __bf16 *__restrict__ Wht,
                                              __bf16 *__restrict__ Wlt) {
  __shared__ float tile[32][256];
  const int wsel = blockIdx.x;
  const int hb = blockIdx.y;
  const float *W = (wsel == 0) ? Wq : (wsel == 1) ? Wk : Wv;
  __bf16 *oh = Wht + wsel * HID * HID;
  __bf16 *ol = Wlt + wsel * HID * HID;
  const int t = threadIdx.x;
  #pragma unroll
  for (int p = 0; p < 8; ++p) {
    int r = p * 4 + (t >> 6);
    int c = (t & 63) * 4;
    *(floatx4 *)&tile[r][c] = *(const floatx4 *)&W[(hb * 32 + r) * HID + c];
  }
  __syncthreads();
  #pragma unroll
  for (int q = 0; q < 4; ++q) {
    int n = q * 64 + (t >> 2);
    int hs = (t & 3) * 8;
    bf16x8 hh, ll;
    #pragma unroll
    for (int i = 0; i < 8; ++i) {
      float v = tile[hs + i][n];
      __bf16 h, l;
      split_bf16(v, h, l);
      hh[i] = h; ll[i] = l;
    }
    *(bf16x8 *)&oh[n * HID + hb * 32 + hs] = hh;
    *(bf16x8 *)&ol[n * HID + hb * 32 + hs] = ll;
  }
}

// ---------------------------------------------------------------------------
// Kernel 2: QKV projection (3-product split-bf16 GEMM, unchanged math).
// W tiles staged in LDS (xor-swizzle) with next-phase reg-prefetch. Epilogues
// now emit SINGLE fp16 planes: Q row-major (scaled), K/V fragment-linear via
// one LDS scratch transpose. grid = (256 m-tiles, 4 col-tiles), 2 blocks/CU.
// ---------------------------------------------------------------------------
__global__ __launch_bounds__(256, 2) void qkv_proj(const float *__restrict__ X,
                                                   const __bf16 *__restrict__ Wht,
                                                   const __bf16 *__restrict__ Wlt,
                                                   _Float16 *__restrict__ Qf,
                                                   _Float16 *__restrict__ Kf,
                                                   _Float16 *__restrict__ Vf) {
  __shared__ __bf16 WhS[64 * 256];
  __shared__ __bf16 WlS[64 * 256];
  _Float16 *Tf = (_Float16 *)WhS;  // 64 x 72 fp16 scratch (aliases WhS)

  const int mtile = blockIdx.x;
  const int col0 = blockIdx.y * 64;
  const int tid = threadIdx.x;
  const int w4 = tid >> 6;
  const int lane = tid & 63;
  const int quad = lane >> 4;
  const int ln = lane & 15;
  const int arow = mtile * 64 + w4 * 16 + ln;

  bf16x8 ah[8], al[8];
  #pragma unroll
  for (int kc = 0; kc < 8; ++kc) {
    const float *xp = X + (size_t)arow * HID + kc * 32 + quad * 8;
    floatx4 x0 = *(const floatx4 *)xp;
    floatx4 x1 = *(const floatx4 *)(xp + 4);
    #pragma unroll
    for (int j = 0; j < 4; ++j) {
      __bf16 h, l;
      split_bf16(x0[j], h, l); ah[kc][j] = h; al[kc][j] = l;
      split_bf16(x1[j], h, l); ah[kc][4 + j] = h; al[kc][4 + j] = l;
    }
  }

  const int srow = tid >> 2;
  const int sseg = tid & 3;

  bf16x8 pwh[8], pwl[8];
  {
    const size_t wbase = (size_t)(col0 + srow) * HID;
    #pragma unroll
    for (int j = 0; j < 8; ++j) {
      const int chunk = j * 4 + sseg;
      pwh[j] = *(const bf16x8 *)&Wht[wbase + chunk * 8];
      pwl[j] = *(const bf16x8 *)&Wlt[wbase + chunk * 8];
    }
  }

  for (int w = 0; w < 3; ++w) {
    __syncthreads();  // W region free (prev MFMA reads / scratch reads done)
    #pragma unroll
    for (int j = 0; j < 8; ++j) {
      const int chunk = j * 4 + sseg;
      const int dst = srow * 256 + ((chunk ^ (srow & 7)) << 3);
      *(bf16x8 *)&WhS[dst] = pwh[j];
      *(bf16x8 *)&WlS[dst] = pwl[j];
    }
    __syncthreads();

    if (w < 2) {
      const size_t wbase = (size_t)(w + 1) * HID * HID + (size_t)(col0 + srow) * HID;
      #pragma unroll
      for (int j = 0; j < 8; ++j) {
        const int chunk = j * 4 + sseg;
        pwh[j] = *(const bf16x8 *)&Wht[wbase + chunk * 8];
        pwl[j] = *(const bf16x8 *)&Wlt[wbase + chunk * 8];
      }
    }

    floatx4 acc[4] = {};
    #pragma unroll
    for (int kc = 0; kc < 8; ++kc) {
      #pragma unroll
      for (int nt = 0; nt < 4; ++nt) {
        const int a = (nt * 16 + ln) * 256 + (((kc * 4 + quad) ^ (ln & 7)) << 3);
        bf16x8 bh = *(const bf16x8 *)&WhS[a];
        bf16x8 bl = *(const bf16x8 *)&WlS[a];
        acc[nt] = MFMA16B(ah[kc], bh, acc[nt]);
        acc[nt] = MFMA16B(ah[kc], bl, acc[nt]);
        acc[nt] = MFMA16B(al[kc], bh, acc[nt]);
      }
    }

    // Epilogues. C/D layout: col = lane&15, row = quad*4 + reg.
    if (w == 0) {
      #pragma unroll
      for (int nt = 0; nt < 4; ++nt) {
        #pragma unroll
        for (int r = 0; r < 4; ++r) {
          const int orow = mtile * 64 + w4 * 16 + quad * 4 + r;
          const int ocol = col0 + nt * 16 + ln;
          Qf[(size_t)orow * HID + ocol] = (_Float16)(acc[nt][r] * QSCALE);
        }
      }
    } else if (w == 1) {
      __syncthreads();  // all MFMA reads of WhS done before scratch clobber
      #pragma unroll
      for (int nt = 0; nt < 4; ++nt) {
        #pragma unroll
        for (int r = 0; r < 4; ++r) {
          const int tok_l = w4 * 16 + quad * 4 + r;
          const int h_l = nt * 16 + ln;
          Tf[tok_l * 72 + h_l] = (_Float16)acc[nt][r];
        }
      }
      __syncthreads();
      #pragma unroll
      for (int i = 0; i < 2; ++i) {     // 512 chunks of 16B
        const int c = i * 256 + tid;
        const int lane_f = c & 63;
        const int ntf = (c >> 6) & 1;
        const int kcL = (c >> 7) & 1;
        const int t2 = (c >> 8) & 1;
        const int qf = lane_f >> 4;
        const int lnf = lane_f & 15;
        const int tok_l = t2 * 32 + ntf * 16 + lnf;
        f16x8 v = *(const f16x8 *)&Tf[tok_l * 72 + kcL * 32 + qf * 8];
        const int T = mtile * 2 + t2;
        const int kc = (col0 >> 5) + kcL;
        *(f16x8 *)&Kf[(size_t)T * 8192 + ((ntf * 8 + kc) * 64 + lane_f) * 8] = v;
      }
    } else {
      __syncthreads();
      #pragma unroll
      for (int nt = 0; nt < 4; ++nt) {
        #pragma unroll
        for (int r = 0; r < 4; ++r) {
          const int tok_l = w4 * 16 + quad * 4 + r;
          const int d_l = nt * 16 + ln;
          Tf[d_l * 72 + tok_l] = (_Float16)acc[nt][r];
        }
      }
      __syncthreads();
      #pragma unroll
      for (int i = 0; i < 2; ++i) {     // 512 chunks of 16B
        const int c = i * 256 + tid;
        const int lane_f = c & 63;
        const int dtL = (c >> 6) & 3;
        const int t2 = (c >> 8) & 1;
        const int qf = lane_f >> 4;
        const int lnf = lane_f & 15;
        const int d_l = dtL * 16 + lnf;
        f16x8 v = *(const f16x8 *)&Tf[d_l * 72 + t2 * 32 + qf * 8];
        const int T = mtile * 2 + t2;
        const int dt = (col0 >> 4) + dtL;
        *(f16x8 *)&Vf[(size_t)(T * 16 + dt) * 512 + lane_f * 8] = v;
      }
    }
  }
}

// ---------------------------------------------------------------------------
// Kernel 3: flash attention, all-fp16 operands. grid = 512 (qt=bx>>1, ks=bx&1),
// 256 thr, 2 blocks/CU (LDS 41 KB). Per 64-key macro: DMA-dbuf KS0/KS1 (16 KB
// tiles, one barrier each), single-product fp16 QK (2-way kc-split chains),
// ONE softmax/P-round-trip/rescale. V direct from global; DPP reductions;
// alpha-skip.
// ---------------------------------------------------------------------------
__global__ __launch_bounds__(256, 2) void attn(const _Float16 *__restrict__ Qf,
                                               const _Float16 *__restrict__ Kf,
                                               const _Float16 *__restrict__ Vf,
                                               _Float16 *__restrict__ Op,
                                               float *__restrict__ Mp,
                                               float *__restrict__ Lp) {
  __shared__ _Float16 KS0[8192];
  __shared__ _Float16 KS1[8192];
  __shared__ _Float16 PsS[4 * 16 * 72];

  const int bx = blockIdx.x;
  const int ks = bx & 1;
  const int qt = bx >> 1;
  const int b = qt >> 6;
  const int qtl = qt & 63;
  const int tid = threadIdx.x;
  const int w4 = tid >> 6;
  const int lane = tid & 63;
  const int quad = lane >> 4;
  const int ln = lane & 15;
  const int T0 = b * 128 + ks * 64;

  const int qtok = b * LSEQ + qtl * 64 + w4 * 16 + ln;
  f16x8 q[8];
  #pragma unroll
  for (int kc = 0; kc < 8; ++kc)
    q[kc] = *(const f16x8 *)&Qf[(size_t)qtok * HID + kc * 32 + quad * 8];

  // Uniform bases (SALU) + fixed per-lane offsets.
  const _Float16 *kuni = Kf + (size_t)T0 * 8192;
  const _Float16 *vuni = Vf + (size_t)T0 * 8192;
  const int koff = tid * 8;
  const int voff = lane * 8;

  // Prologue: DMA tile 0 -> KS0 (4 rounds x 4 KB).
  #pragma unroll
  for (int i = 0; i < 4; ++i)
    GLOAD_LDS16(kuni + i * 2048 + koff, &KS0[i * 2048 + koff]);

  float m[4] = {-1e30f, -1e30f, -1e30f, -1e30f};
  float l[4] = {0.f, 0.f, 0.f, 0.f};
  floatx4 o[16] = {};

  for (int jm = 0; jm < 32; ++jm) {
    floatx4 s[4];
    // ---------- tile A (keys 64*jm..+31) from KS0 ----------
    __syncthreads();  // drains KS0's DMA; all waves done reading KS1 (prev macro)
    {
      const _Float16 *src = kuni + (size_t)(2 * jm + 1) * 8192 + koff;
      #pragma unroll
      for (int i = 0; i < 4; ++i)
        GLOAD_LDS16(src + i * 2048, &KS1[i * 2048 + koff]);
    }
    {
      floatx4 pa[2] = {}, pb[2] = {};
      #pragma unroll
      for (int nt = 0; nt < 2; ++nt)
        #pragma unroll
        for (int kc = 0; kc < 4; ++kc) {
          pa[nt] = MFMA16F(q[kc], *(const f16x8 *)(KS0 + (nt * 8 + kc) * 512 + voff), pa[nt]);
          pb[nt] = MFMA16F(q[4 + kc], *(const f16x8 *)(KS0 + (nt * 8 + 4 + kc) * 512 + voff), pb[nt]);
        }
      s[0] = pa[0] + pb[0];
      s[1] = pa[1] + pb[1];
    }
    // ---------- tile B (keys +32..+63) from KS1 ----------
    __syncthreads();  // drains KS1's DMA; all waves done reading KS0
    if (jm < 31) {
      const _Float16 *src = kuni + (size_t)(2 * jm + 2) * 8192 + koff;
      #pragma unroll
      for (int i = 0; i < 4; ++i)
        GLOAD_LDS16(src + i * 2048, &KS0[i * 2048 + koff]);
    }
    const _Float16 *va = vuni + (size_t)(2 * jm) * 8192;
    const _Float16 *vbp = vuni + (size_t)(2 * jm + 1) * 8192;
    f16x8 vb0[8];
    #pragma unroll
    for (int dt = 0; dt < 8; ++dt)
      vb0[dt] = *(const f16x8 *)(va + dt * 512 + voff);
    {
      floatx4 pa[2] = {}, pb[2] = {};
      #pragma unroll
      for (int nt = 0; nt < 2; ++nt)
        #pragma unroll
        for (int kc = 0; kc < 4; ++kc) {
          pa[nt] = MFMA16F(q[kc], *(const f16x8 *)(KS1 + (nt * 8 + kc) * 512 + voff), pa[nt]);
          pb[nt] = MFMA16F(q[4 + kc], *(const f16x8 *)(KS1 + (nt * 8 + 4 + kc) * 512 + voff), pb[nt]);
        }
      s[2] = pa[0] + pb[0];
      s[3] = pa[1] + pb[1];
    }
    f16x8 vb1[8];
    #pragma unroll
    for (int dt = 0; dt < 8; ++dt)
      vb1[dt] = *(const f16x8 *)(va + (8 + dt) * 512 + voff);

    // ---------- softmax over 64 keys (base-2, DPP) ----------
    float alpha[4];
    #pragma unroll
    for (int r = 0; r < 4; ++r) {
      const float tmax = row_max16(
          fmaxf(fmaxf(s[0][r], s[1][r]), fmaxf(s[2][r], s[3][r])));
      const float mn = fmaxf(m[r], tmax);
      const float al = exp2f(m[r] - mn);
      const float p0 = exp2f(s[0][r] - mn);
      const float p1 = exp2f(s[1][r] - mn);
      const float p2 = exp2f(s[2][r] - mn);
      const float p3 = exp2f(s[3][r] - mn);
      s[0][r] = p0; s[1][r] = p1; s[2][r] = p2; s[3][r] = p3;
      const float rs = row_sum16((p0 + p1) + (p2 + p3));
      l[r] = l[r] * al + rs;
      m[r] = mn;
      alpha[r] = al;
    }

    // ---------- P write (C-layout -> A-layout via per-wave LDS) ----------
    _Float16 *ps = PsS + w4 * 16 * 72;
    #pragma unroll
    for (int nt = 0; nt < 4; ++nt)
      #pragma unroll
      for (int r = 0; r < 4; ++r)
        ps[(quad * 4 + r) * 72 + nt * 16 + ln] = (_Float16)s[nt][r];

    // ---------- O rescale (alpha-skip; near-one-hot -> mostly skipped) ------
    const float amin = fminf(fminf(alpha[0], alpha[1]), fminf(alpha[2], alpha[3]));
    if (__any(amin < 1.0f)) {
      #pragma unroll
      for (int dt = 0; dt < 16; ++dt) {
        o[dt][0] *= alpha[0]; o[dt][1] *= alpha[1];
        o[dt][2] *= alpha[2]; o[dt][3] *= alpha[3];
      }
    }

    const f16x8 paA = *(const f16x8 *)&ps[ln * 72 + quad * 8];
    const f16x8 paB = *(const f16x8 *)&ps[ln * 72 + 32 + quad * 8];

    // ---------- O += P V (two 32-key halves) ----------
    #pragma unroll
    for (int dt = 0; dt < 8; ++dt) o[dt] = MFMA16F(paA, vb0[dt], o[dt]);
    f16x8 vb2[8];
    #pragma unroll
    for (int dt = 0; dt < 8; ++dt)
      vb2[dt] = *(const f16x8 *)(vbp + dt * 512 + voff);
    #pragma unroll
    for (int dt = 0; dt < 8; ++dt) o[8 + dt] = MFMA16F(paA, vb1[dt], o[8 + dt]);
    f16x8 vb3[8];
    #pragma unroll
    for (int dt = 0; dt < 8; ++dt)
      vb3[dt] = *(const f16x8 *)(vbp + (8 + dt) * 512 + voff);
    #pragma unroll
    for (int dt = 0; dt < 8; ++dt) o[dt] = MFMA16F(paB, vb2[dt], o[dt]);
    #pragma unroll
    for (int dt = 0; dt < 8; ++dt) o[8 + dt] = MFMA16F(paB, vb3[dt], o[8 + dt]);
  }

  const int rowbase = b * LSEQ + qtl * 64 + w4 * 16 + quad * 4;
  #pragma unroll
  for (int dt = 0; dt < 16; ++dt)
    #pragma unroll
    for (int r = 0; r < 4; ++r)
      Op[(size_t)ks * PLANE + (size_t)(rowbase + r) * HID + dt * 16 + ln] =
          (_Float16)o[dt][r];
  if (ln == 0) {
    #pragma unroll
    for (int r = 0; r < 4; ++r) {
      Mp[ks * NTOK + rowbase + r] = m[r];
      Lp[ks * NTOK + rowbase + r] = l[r];
    }
  }
}

// ---------------------------------------------------------------------------
// Kernel 4: split-K merge (fp16 partials).
// ---------------------------------------------------------------------------
__global__ __launch_bounds__(256) void merge(const _Float16 *__restrict__ Op,
                                             const float *__restrict__ Mp,
                                             const float *__restrict__ Lp,
                                             float *__restrict__ Out) {
  const int row = blockIdx.x * 4 + (threadIdx.x >> 6);
  const int c = (threadIdx.x & 63) * 4;
  const float m0 = Mp[row], m1 = Mp[NTOK + row];
  const float l0 = Lp[row], l1 = Lp[NTOK + row];
  const float M = fmaxf(m0, m1);
  const float e0 = exp2f(m0 - M), e1 = exp2f(m1 - M);
  const float invL = 1.0f / (l0 * e0 + l1 * e1);
  const float w0 = e0 * invL, w1 = e1 * invL;
  f16x4 a = *(const f16x4 *)&Op[(size_t)row * HID + c];
  f16x4 b4 = *(const f16x4 *)&Op[PLANE + (size_t)row * HID + c];
  floatx4 out;
  #pragma unroll
  for (int i = 0; i < 4; ++i) out[i] = w0 * (float)a[i] + w1 * (float)b4[i];
  *(floatx4 *)&Out[(size_t)row * HID + c] = out;
}

// ---------------------------------------------------------------------------
extern "C" void kernel_launch(void *const *d_in, const int *in_sizes, int n_in,
                              void *d_out, int out_size, void *d_ws, size_t ws_size,
                              hipStream_t stream) {
  const float *X = (const float *)d_in[0];
  const float *Wq = (const float *)d_in[1];
  const float *Wk = (const float *)d_in[2];
  const float *Wv = (const float *)d_in[3];
  // d_in[4] = lengths (unused by reference)

  // Workspace (2-byte elements). ~42 MB total.
  _Float16 *ws = (_Float16 *)d_ws;
  _Float16 *Qf = ws;                          // [16384][256] row-major fp16
  _Float16 *Kf = Qf + PLANE;                  // 32-key frag-linear fp16
  _Float16 *Vf = Kf + PLANE;                  // 32-key frag-linear fp16
  __bf16 *Wht = (__bf16 *)(Vf + PLANE);       // [3][256][256] bf16 hi
  __bf16 *Wlt = Wht + 3 * HID * HID;          // bf16 lo
  _Float16 *Op = (_Float16 *)(Wlt + 3 * HID * HID);  // [2][16384][256] fp16
  float *Mp = (float *)(Op + 2 * PLANE);      // [2][16384]
  float *Lp = Mp + 2 * NTOK;                  // [2][16384]

  wsplit<<<dim3(3, 8), 256, 0, stream>>>(Wq, Wk, Wv, Wht, Wlt);
  qkv_proj<<<dim3(256, 4), 256, 0, stream>>>(X, Wht, Wlt, Qf, Kf, Vf);
  attn<<<512, 256, 0, stream>>>(Qf, Kf, Vf, Op, Mp, Lp);
  merge<<<NTOK / 4, 256, 0, stream>>>(Op, Mp, Lp, (float *)d_out);
}